// Round 12
// baseline (187.040 us; speedup 1.0000x reference)
//
#include <hip/hip_runtime.h>

// SimpleSNN: T=16, B=4096, N_IN=784, N_HID=256, N_OUT=10
//   conv_x      : X fp32 {0,1} -> Xq4 NIBBLES (4-bit), K padded 784->832.
//                 27.2 MB -> per-XCD working set 3.4 MB: A becomes L2-resident.
//   conv_w3     : W1 -> 3 i8 planes, w = 2^-11 a + 2^-18 b + 2^-25 c
//                 (residual <= 2^-26; i32 MFMA accumulation exact)
//   gemm1_lif1  : FUSED, t-tiled x4. Block 64 rows x 32 cols (ns=8), 4 waves
//                 of 16r x 32c; W in LDS once (81,408 B, 2 blocks/CU), zero
//                 barriers in loop. A: uint2 nibble loads (rolling 3-deep,
//                 static idx) + v_perm unpack to i8 {0,1}. 24 MFMA/k-step.
//                 B ds_reads amortized /4 over timesteps. LIF in regs -> z1 i8.
//   gemm2_f32   : z1 i8 -> fp32 (exact), identical dot order
//   lif2        : unchanged

#define T_STEPS 16
#define B_SZ    4096
#define N_IN    784
#define N_HID   256
#define N_OUT   10
#define M_TOT   (T_STEPS * B_SZ)   // 65536
#define KP8     832                // 13 * 64
#define KNB     416                // nibble bytes per row (832/2)
#define WPLANE  (N_HID * KP8)      // i8 elems per W plane (global)
#define WROW    848                // padded LDS row stride (53*16)
#define WPL     (32 * WROW)        // per-plane LDS bytes (27136)

typedef int    i32x4 __attribute__((ext_vector_type(4)));
typedef unsigned int u32;
typedef unsigned char u8;

#if defined(__has_builtin) && __has_builtin(__builtin_amdgcn_perm)
__device__ __forceinline__ u32 ilv(u32 hi, u32 lo) {      // [lo.b0,hi.b0,lo.b1,hi.b1]
    return __builtin_amdgcn_perm(hi, lo, 0x05010400u);
}
__device__ __forceinline__ u32 ilv_hi(u32 hi, u32 lo) {   // [lo.b2,hi.b2,lo.b3,hi.b3]
    return __builtin_amdgcn_perm(hi, lo, 0x07030602u);
}
#else
__device__ __forceinline__ u32 ilv(u32 hi, u32 lo) {
    return (lo & 0xFFu) | ((hi & 0xFFu) << 8) |
           ((lo & 0xFF00u) << 8) | ((hi & 0xFF00u) << 16);
}
__device__ __forceinline__ u32 ilv_hi(u32 hi, u32 lo) { return ilv(hi >> 16, lo >> 16); }
#endif

// unpack 8 nibble-bytes (16 k-values) -> 16 i8 bytes {0,1}
__device__ __forceinline__ uint4 unp(uint2 u) {
    const u32 lo0 = u.x & 0x0F0F0F0Fu, hi0 = (u.x >> 4) & 0x0F0F0F0Fu;
    const u32 lo1 = u.y & 0x0F0F0F0Fu, hi1 = (u.y >> 4) & 0x0F0F0F0Fu;
    uint4 r;
    r.x = ilv(hi0, lo0);
    r.y = ilv_hi(hi0, lo0);
    r.z = ilv(hi1, lo1);
    r.w = ilv_hi(hi1, lo1);
    return r;
}

// ---------------- conv_x: fp32 {0,1} -> nibbles, pad K 784->832 ------------
__global__ __launch_bounds__(256) void conv_x(
    const float* __restrict__ X, u8* __restrict__ Xq4)
{
    const long idx = (long)blockIdx.x * 256 + threadIdx.x;   // < 65536*52
    const long m = idx / 52;
    const int  s = (int)(idx - m * 52);                      // 16-k unit
    uint2 o = make_uint2(0u, 0u);
    if (s < 49) {                                  // 49*16 = 784 exactly
        const uint4* src = reinterpret_cast<const uint4*>(X + m * N_IN + s * 16);
        const uint4 f0 = src[0], f1 = src[1], f2 = src[2], f3 = src[3];
        auto nib = [](uint4 a, uint4 b) -> u32 {   // 8 floats -> 8 nibbles
            return (a.x ? 1u : 0u)        | ((a.y ? 1u : 0u) << 4)  |
                   ((a.z ? 1u : 0u) << 8) | ((a.w ? 1u : 0u) << 12) |
                   ((b.x ? 1u : 0u) << 16)| ((b.y ? 1u : 0u) << 20) |
                   ((b.z ? 1u : 0u) << 24)| ((b.w ? 1u : 0u) << 28);
        };
        o.x = nib(f0, f1);
        o.y = nib(f2, f3);
    }
    reinterpret_cast<uint2*>(Xq4)[idx] = o;
}

// ---------------- conv_w3: W1 -> 3 i8 planes (power-of-2 scales) -----------
__global__ __launch_bounds__(256) void conv_w3(
    const float* __restrict__ W1, char* __restrict__ Wq)
{
    const int idx = blockIdx.x * 256 + threadIdx.x;   // over 256*832
    if (idx >= N_HID * KP8) return;
    const int n = idx / KP8, k = idx % KP8;
    const float w = (k < N_IN) ? W1[n * N_IN + k] : 0.0f;
    const float a = rintf(w * 2048.0f);                       // s1 = 2^-11
    const float r1 = fmaf(a, -4.8828125e-4f, w);
    const float b = rintf(r1 * 262144.0f);                    // s2 = 2^-18
    const float r2 = fmaf(b, -3.814697265625e-6f, r1);
    const float c = rintf(r2 * 33554432.0f);                  // s3 = 2^-25
    Wq[idx]              = (char)(int)a;
    Wq[WPLANE + idx]     = (char)(int)b;
    Wq[2 * WPLANE + idx] = (char)(int)c;
}

// ---------------- gemm1 + lif1 fused, nibble A, t-tiled x4 -----------------
__global__ __launch_bounds__(256, 2) void gemm1_lif1(
    const u8* __restrict__ Xq4,
    const u8* __restrict__ Wq,
    const float* __restrict__ b1,
    u8* __restrict__ Z1)
{
    __shared__ u8 Bq[3 * WPL];          // 81,408 B -> exactly 2 blocks/CU

    const int tid  = threadIdx.x;
    const int lane = tid & 63;
    const int w    = tid >> 6;          // wave 0..3: rows w*16..+16
    // XCD grouping: 8 b-tiles x 8 n-slices per XCD (working set 3.4 MB < L2)
    const int bid = blockIdx.x;
    const int l   = (bid & 7) * 64 + (bid >> 3);
    const int b0  = (l >> 3) * 64;      // 64 b-tiles of 64 rows
    const int n0  = (l & 7) * 32;       // 8 n-slices of 32 cols
    const int ls  = lane >> 4;          // k-slice 0..3
    const int lr  = lane & 15;

    // ---- W -> LDS via regs (row stride 848: benign bank spread) ----
    #pragma unroll
    for (int it = 0; it < 20; ++it) {
        const int u = it * 256 + tid;                 // 3*32*52 = 4992 units
        if (u < 4992) {
            const int plane = u / 1664;
            const int rem   = u - plane * 1664;
            const int col   = rem / 52;
            const int sp    = rem - col * 52;
            const uint4 v = *reinterpret_cast<const uint4*>(
                Wq + (size_t)plane * WPLANE + (size_t)(n0 + col) * KP8 + sp * 16);
            *reinterpret_cast<uint4*>(&Bq[plane * WPL + col * WROW + sp * 16]) = v;
        }
    }
    __syncthreads();                    // the only barrier

    const float bb0 = b1[n0 + lr];
    const float bb1 = b1[n0 + 16 + lr];
    float vS[8], cS[8];                 // LIF state per (cf,q) = cf*4+q
    #pragma unroll
    for (int k = 0; k < 8; ++k) { vS[k] = 0.0f; cS[k] = 0.0f; }

    int bO[2][3];
    #pragma unroll
    for (int cf = 0; cf < 2; ++cf)
        #pragma unroll
        for (int p = 0; p < 3; ++p)
            bO[cf][p] = p * WPL + (cf * 16 + lr) * WROW + (ls << 4);

    const size_t TS = (size_t)B_SZ * KNB;     // per-t A stride (nibble bytes)
    const u8* aPtr = Xq4 + (size_t)(b0 + w * 16 + lr) * KNB + ls * 8;

    const float s1 = 4.8828125e-4f;          // 2^-11
    const float s2 = 3.814697265625e-6f;     // 2^-18
    const float s3 = 2.9802322387695312e-8f; // 2^-25

    for (int g = 0; g < 4; ++g) {       // 4 groups x 4 timesteps
        i32x4 acc[4][2][3];
        #pragma unroll
        for (int tt = 0; tt < 4; ++tt)
            #pragma unroll
            for (int cf = 0; cf < 2; ++cf)
                #pragma unroll
                for (int p = 0; p < 3; ++p)
                    acc[tt][cf][p] = (i32x4){0, 0, 0, 0};

        uint2 ar[3][4];                 // rolling A buffers (static mod-3 idx)
        #pragma unroll
        for (int tt = 0; tt < 4; ++tt) {
            ar[0][tt] = *reinterpret_cast<const uint2*>(aPtr + tt * TS);
            ar[1][tt] = *reinterpret_cast<const uint2*>(aPtr + tt * TS + 32);
        }

        #pragma unroll
        for (int kt = 0; kt < 13; ++kt) {
            if (kt + 2 < 13) {          // prefetch 2 k-steps ahead
                #pragma unroll
                for (int tt = 0; tt < 4; ++tt)
                    ar[(kt + 2) % 3][tt] = *reinterpret_cast<const uint2*>(
                        aPtr + tt * TS + (kt + 2) * 32);
            }
            uint4 bf[2][3];
            #pragma unroll
            for (int cf = 0; cf < 2; ++cf)
                #pragma unroll
                for (int p = 0; p < 3; ++p)
                    bf[cf][p] = *reinterpret_cast<const uint4*>(&Bq[bO[cf][p] + kt * 64]);
            uint4 af[4];
            #pragma unroll
            for (int tt = 0; tt < 4; ++tt)
                af[tt] = unp(ar[kt % 3][tt]);

            __builtin_amdgcn_s_setprio(1);
            #pragma unroll
            for (int tt = 0; tt < 4; ++tt)
                #pragma unroll
                for (int cf = 0; cf < 2; ++cf)
                    #pragma unroll
                    for (int p = 0; p < 3; ++p)
                        acc[tt][cf][p] = __builtin_amdgcn_mfma_i32_16x16x64_i8(
                            __builtin_bit_cast(i32x4, af[tt]),
                            __builtin_bit_cast(i32x4, bf[cf][p]),
                            acc[tt][cf][p], 0, 0, 0);
            __builtin_amdgcn_s_setprio(0);
        }
        aPtr += 4 * TS;

        // LIF for the 4 timesteps, in order; write spikes as i8
        #pragma unroll
        for (int tt = 0; tt < 4; ++tt) {
            const int t = 4 * g + tt;
            #pragma unroll
            for (int cf = 0; cf < 2; ++cf) {
                #pragma unroll
                for (int q = 0; q < 4; ++q) {
                    const int k = cf * 4 + q;
                    const float c1 = fmaf(s1, (float)acc[tt][cf][0][q],
                                     fmaf(s2, (float)acc[tt][cf][1][q],
                                     fmaf(s3, (float)acc[tt][cf][2][q],
                                          cf ? bb1 : bb0)));
                    const float vd = vS[k] + 0.1f * ((0.0f - vS[k]) + cS[k]);
                    const float id = cS[k] - 0.2f * cS[k];
                    const bool  sp = vd > 1.0f;
                    Z1[(size_t)(t * B_SZ + b0 + w * 16 + ls * 4 + q) * N_HID
                       + n0 + cf * 16 + lr] = sp ? (u8)1 : (u8)0;
                    vS[k] = sp ? 0.0f : vd;
                    cS[k] = id + c1;
                }
            }
        }
    }
}

// ---------------- GEMM2: z1 i8 -> fp32 (exact), K=256, N=10 ----------------
__global__ __launch_bounds__(640) void gemm2_f32(
    const u8* __restrict__ Z, const float* __restrict__ W2,
    const float* __restrict__ b2, float* __restrict__ C2)
{
    __shared__ float zs[64 * 268];
    __shared__ float ws[N_OUT * N_HID];
    const int tid = threadIdx.x;
    const int m0 = blockIdx.x * 64;

    for (int c = tid; c < 1024; c += 640) {          // 64 rows x 16 chunks
        const int r = c >> 4;
        const int col = (c & 15) * 16;
        const uint4 v = *reinterpret_cast<const uint4*>(
            Z + (size_t)(m0 + r) * N_HID + col);
        float* d = &zs[r * 268 + col];
        const u32 wd[4] = {v.x, v.y, v.z, v.w};
        #pragma unroll
        for (int k = 0; k < 4; ++k)
            #pragma unroll
            for (int b = 0; b < 4; ++b)
                d[k * 4 + b] = (float)((wd[k] >> (8 * b)) & 0xffu);
    }
    *(float4*)&ws[tid * 4] = *(const float4*)&W2[tid * 4];
    __syncthreads();

    const int o = tid >> 6;
    const int r = tid & 63;
    float acc = b2[o];
    #pragma unroll
    for (int k = 0; k < N_HID; k += 4) {
        const float4 z4 = *(const float4*)&zs[r * 268 + k];
        const float4 w4 = *(const float4*)&ws[o * N_HID + k];
        acc += z4.x * w4.x + z4.y * w4.y + z4.z * w4.z + z4.w * w4.w;
    }
    C2[(size_t)(m0 + r) * N_OUT + o] = acc;
}

// ---------------- LIF2: per (b,o), loop t; accumulate spike count ----------
__global__ __launch_bounds__(256) void lif2_kernel(
    const float* __restrict__ C2, float* __restrict__ out)
{
    const int g = blockIdx.x * 256 + threadIdx.x;
    const int stride = B_SZ * N_OUT;
    float v = 0.0f, cur = 0.0f, s = 0.0f;
    #pragma unroll
    for (int t = 0; t < T_STEPS; ++t) {
        const float c = C2[t * stride + g];
        const float vd = v + 0.1f * ((0.0f - v) + cur);
        const float id = cur - 0.2f * cur;
        const bool  sp = vd > 1.0f;
        s += sp ? 1.0f : 0.0f;
        v = sp ? 0.0f : vd;
        cur = id + c;
    }
    out[g] = s;
}

extern "C" void kernel_launch(void* const* d_in, const int* in_sizes, int n_in,
                              void* d_out, int out_size, void* d_ws, size_t ws_size,
                              hipStream_t stream)
{
    const float* X  = (const float*)d_in[0];
    const float* W1 = (const float*)d_in[1];
    const float* b1 = (const float*)d_in[2];
    const float* W2 = (const float*)d_in[3];
    const float* b2 = (const float*)d_in[4];
    float* out = (float*)d_out;

    // ws: [Wq 0.64MB | pad->1MB][Xq4 27.3MB][Z1 16.8MB][C2 2.6MB]
    char* Wq = (char*)d_ws;
    u8*   Xq4 = (u8*)d_ws + (1 << 20);
    u8*   Z1 = Xq4 + (size_t)M_TOT * KNB;
    float* C2 = (float*)(Z1 + (size_t)M_TOT * N_HID);

    conv_x<<<(M_TOT * 52) / 256, 256, 0, stream>>>(X, Xq4);

    conv_w3<<<(N_HID * KP8) / 256, 256, 0, stream>>>(W1, Wq);

    gemm1_lif1<<<512, 256, 0, stream>>>(Xq4, (const u8*)Wq, b1, Z1);

    gemm2_f32<<<M_TOT / 64, 640, 0, stream>>>(Z1, W2, b2, C2);

    lif2_kernel<<<(B_SZ * N_OUT) / 256, 256, 0, stream>>>(C2, out);
}